// Round 12
// baseline (114.372 us; speedup 1.0000x reference)
//
#include <hip/hip_runtime.h>
#include <hip/hip_bf16.h>

// Problem: B=32, S=512, P=512, D=768
//   M = B*S = 16384 tokens, N = P = 512 prototypes, K = D = 768
// out[0 .. M*N)            = distances  ||x_m - p_n||^2  (fp32)
// out[M*N .. M*N + N*K)    = prototypes (fp32 passthrough)
//
// R17 = R10 (8-wave, fragment-major B; best at 102.6us) + WINDOWED
// REGISTER-BURST PIPELINE.
//   R16 autopsy: issue-pinning worked but gained 0 because vmcnt retires
//   IN ORDER -- the K-loop's per-iteration B-prefetch waits confirm loads
//   newer than the staged burst, draining it after ~1 k-step. Rule learned:
//   a load burst only overlaps K-loop work that waits on loads issued
//   BEFORE the burst. R17 obeys it: K split into 8 windows of 3 k-steps;
//   per window, FIRST issue next window's B frags into REGISTERS (12 loads),
//   THEN the next A-section stage loads (3 float4), sched_barrier(0) pin,
//   then 3 k-steps consuming the PREVIOUS burst from registers (first use =
//   counted vmcnt, burst w older than burst w+1 + stage w+1 -> no drain),
//   then convert+ds_write staged section, barrier. Per-CU per window:
//   stage 24.5KB ~1.0us ~ MFMA 0.78us -> balanced; staging (~8us serial in
//   R10) rides under the K-loop.
//   Unchanged: grid 256 (1 block/CU, X read once, B 201MB L2), full-K
//   97KB LDS single buffer, fragment-major coalesced B, 4x4 acc, epilogue.

#define M_TOK 16384
#define N_PROT 512
#define K_DIM 768
#define BK 32
#define NW 8                 // windows
#define SPW 3                // k-steps per window (K=96 per window)
#define ASTR (K_DIM + 8)     // 776: padded LDS row stride in bf16 units

typedef __attribute__((ext_vector_type(4))) float f32x4;
typedef __attribute__((ext_vector_type(8))) short bf16x8;

__device__ inline unsigned short f2bf(float f) {
    // round-to-nearest-even on the bit pattern (finite inputs)
    unsigned int u = __float_as_uint(f);
    u += 0x7fffu + ((u >> 16) & 1u);
    return (unsigned short)(u >> 16);
}

// One wave per prototype row: bf16 convert (fragment-major store) + ||p||^2
// + fp32 passthrough copy.  (unchanged from verified R10)
__global__ __launch_bounds__(256) void prep_b(
    const float* __restrict__ p,
    unsigned short* __restrict__ b_bf, float* __restrict__ p_sq,
    float* __restrict__ proto_out)
{
    const int row  = blockIdx.x * 4 + (threadIdx.x >> 6);
    const int lane = threadIdx.x & 63;

    const int g    = row >> 4;          // proto group 0..31
    const int l16p = row & 15;          // row within group

    const float4* src4 = (const float4*)(p + (size_t)row * K_DIM);
    float4* pout4 = (float4*)(proto_out + (size_t)row * K_DIM);

    float ssum = 0.0f;
#pragma unroll
    for (int j = 0; j < 3; ++j) {        // 192 float4 per row / 64 lanes
        const int idx = lane + j * 64;   // float4 index 0..191
        float4 v = src4[idx];
        ssum += v.x * v.x + v.y * v.y + v.z * v.z + v.w * v.w;
        ushort4 b;
        b.x = f2bf(v.x); b.y = f2bf(v.y); b.z = f2bf(v.z); b.w = f2bf(v.w);
        // fragment-major: element k -> block (g*24 + k>>5), slot
        // ((k>>3)&3)*16 + l16p (lane id), sub-offset k&7.
        const int k0   = idx * 4;               // first element of this ushort4
        const int kk   = k0 >> 5;               // k-step 0..23
        const int quad = (k0 >> 3) & 3;         // k-slice 0..3
        const int j0   = k0 & 7;                // 0 or 4
        const int dst  = (g * 24 + kk) * 512 + quad * 128 + l16p * 8 + j0;
        *(ushort4*)&b_bf[dst] = b;
        pout4[idx] = v;
    }
#pragma unroll
    for (int off = 32; off > 0; off >>= 1) ssum += __shfl_down(ssum, off);
    if (lane == 0) p_sq[row] = ssum;
}

__global__ __launch_bounds__(512, 2) void dist_main(
    const float* __restrict__ X,             // [M,K] fp32 tokens
    const unsigned short* __restrict__ Bb,   // fragment-major bf16 protos (ws)
    const float* __restrict__ p_sq,          // [N] fp32
    float* __restrict__ out)                 // [M,N] fp32 distances
{
    __shared__ unsigned short lds_a[64 * ASTR];   // ~97 KB, full-K A stripe
    __shared__ float lds_xsq[64];

    const int tid  = threadIdx.x;
    const int wave = tid >> 6;           // 0..7
    const int lane = tid & 63;
    const int bm   = blockIdx.x << 6;    // 64-row A stripe
    const int wn   = wave << 6;          // this wave's 64-col slice of N
    const int quad = lane >> 4;          // 0..3
    const int l16  = lane & 15;

    // ---- staging mapping: section = 64 rows x 24 float4 (K=96) ----
    // per section: 1536 float4 / 512 thr = 3 each, c4 = w*24 + ac + 8*j
    const int ar = tid >> 3;             // row 0..63
    const int ac = tid & 7;              // float4 col base 0..7
    const float* aptr = X + (size_t)(bm + ar) * K_DIM;

    float asq = 0.0f;

    // ---- prologue: stage section 0 (cols 0..23 float4) ----
#pragma unroll
    for (int j = 0; j < 3; ++j) {
        const int c4 = ac + 8 * j;
        float4 v = *(const float4*)(aptr + (size_t)c4 * 4);
        asq += v.x * v.x + v.y * v.y + v.z * v.z + v.w * v.w;
        ushort4 u;
        u.x = f2bf(v.x); u.y = f2bf(v.y); u.z = f2bf(v.z); u.w = f2bf(v.w);
        *(ushort4*)&lds_a[ar * ASTR + c4 * 4] = u;
    }
    __syncthreads();

    // ---- fragment-major B: block (g*24+kk)*1KB, lane's 16B at lane*16 ----
    const unsigned short* bp = Bb + (size_t)lane * 8;
    const int gbase = (wave << 2) * 24;          // (wave*4)*24

    const f32x4 zero = {0.0f, 0.0f, 0.0f, 0.0f};
    f32x4 acc[4][4];
#pragma unroll
    for (int mt = 0; mt < 4; ++mt)
#pragma unroll
        for (int nt = 0; nt < 4; ++nt) acc[mt][nt] = zero;

    // preload burst for window 0 (k-steps 0..2, all 4 proto groups)
    bf16x8 bw[SPW][4], bn[SPW][4];
#pragma unroll
    for (int s = 0; s < SPW; ++s)
#pragma unroll
        for (int nt = 0; nt < 4; ++nt)
            bw[s][nt] = *(const bf16x8*)(bp + (size_t)(gbase + nt * 24 + s) * 512);

    // ---- windowed pipeline: w-loop fully unrolled (static reg indices) ----
#pragma unroll
    for (int w = 0; w < NW; ++w) {
        // 1) issue next window's B burst FIRST (so in-window waits on
        //    burst w never force the stage loads below to retire)
        if (w + 1 < NW) {
#pragma unroll
            for (int s = 0; s < SPW; ++s)
#pragma unroll
                for (int nt = 0; nt < 4; ++nt)
                    bn[s][nt] = *(const bf16x8*)(bp
                        + (size_t)(gbase + nt * 24 + (w + 1) * SPW + s) * 512);
        }
        // 2) then issue next A-section stage loads (newest in flight)
        float4 sv[3];
        if (w + 1 < NW) {
#pragma unroll
            for (int j = 0; j < 3; ++j)
                sv[j] = *(const float4*)(aptr
                    + (size_t)((w + 1) * 24 + ac + 8 * j) * 4);
        }
        // 3) pin: nothing above moves below, nothing below moves up
        __builtin_amdgcn_sched_barrier(0);

        // 4) 3 k-steps consuming burst w from REGISTERS (A from LDS)
#pragma unroll
        for (int s = 0; s < SPW; ++s) {
            const int k0 = (w * SPW + s) * BK;
            bf16x8 af[4];
#pragma unroll
            for (int mt = 0; mt < 4; ++mt)
                af[mt] = *(const bf16x8*)&lds_a[(mt * 16 + l16) * ASTR + k0 + quad * 8];
#pragma unroll
            for (int mt = 0; mt < 4; ++mt)
#pragma unroll
                for (int nt = 0; nt < 4; ++nt)
                    acc[mt][nt] = __builtin_amdgcn_mfma_f32_16x16x32_bf16(
                        af[mt], bw[s][nt], acc[mt][nt], 0, 0, 0);
        }

        // 5) convert + ds_write staged section w+1, barrier, rotate burst
        if (w + 1 < NW) {
#pragma unroll
            for (int j = 0; j < 3; ++j) {
                float4 v = sv[j];
                asq += v.x * v.x + v.y * v.y + v.z * v.z + v.w * v.w;
                ushort4 u;
                u.x = f2bf(v.x); u.y = f2bf(v.y); u.z = f2bf(v.z); u.w = f2bf(v.w);
                *(ushort4*)&lds_a[ar * ASTR + ((w + 1) * 24 + ac + 8 * j) * 4] = u;
            }
            __syncthreads();
#pragma unroll
            for (int s = 0; s < SPW; ++s)
#pragma unroll
                for (int nt = 0; nt < 4; ++nt)
                    bw[s][nt] = bn[s][nt];   // SSA-renamed away under full unroll
        }
    }

    // ---- x_sq: reduce over the 8 staging threads of each row ----
#pragma unroll
    for (int off = 1; off < 8; off <<= 1) asq += __shfl_xor(asq, off);
    if (ac == 0) lds_xsq[ar] = asq;
    __syncthreads();

    // ---- epilogue: C/D layout col = lane&15, row = quad*4 + i ----
    float ps[4];
#pragma unroll
    for (int nt = 0; nt < 4; ++nt) ps[nt] = p_sq[wn + nt * 16 + l16];

#pragma unroll
    for (int mt = 0; mt < 4; ++mt) {
#pragma unroll
        for (int i = 0; i < 4; ++i) {
            const int lr = mt * 16 + quad * 4 + i;   // local row 0..63
            const float xs = lds_xsq[lr];
            float* orow = out + (size_t)(bm + lr) * N_PROT + wn + l16;
#pragma unroll
            for (int nt = 0; nt < 4; ++nt)
                orow[nt * 16] = xs + ps[nt] - 2.0f * acc[mt][nt][i];
        }
    }
}

extern "C" void kernel_launch(void* const* d_in, const int* in_sizes, int n_in,
                              void* d_out, int out_size, void* d_ws, size_t ws_size,
                              hipStream_t stream) {
    const float* inputs = (const float*)d_in[0];   // [32,512,768] fp32
    const float* protos = (const float*)d_in[1];   // [512,768]    fp32
    float* out = (float*)d_out;
    float* proto_out = out + (size_t)M_TOK * N_PROT;   // second tuple element

    // ws layout: b_bf 512*768*2 = 786,432 B (fragment-major) ; p_sq 2,048 B
    char* ws = (char*)d_ws;
    unsigned short* b_bf = (unsigned short*)ws;
    float* p_sq = (float*)(ws + 786432);

    prep_b<<<128, 256, 0, stream>>>(protos, b_bf, p_sq, proto_out);
    dist_main<<<M_TOK / 64, 512, 0, stream>>>(inputs, b_bf, p_sq, out);
}